// Round 11
// baseline (2706.150 us; speedup 1.0000x reference)
//
#include <hip/hip_runtime.h>
#include <hip/hip_bf16.h>
#include <math.h>

#define B_ 16
#define S_ 512
#define E_ 300
#define H_ 512
#define V_ 10000
#define BS_ (B_ * S_)  // 8192

#define NSL 16           // slices (blocks) per batch, j-split
#define JPB (H_ / NSL)   // 32 output rows per block
#define NBLK (B_ * NSL)  // 256 blocks in the scan

typedef __attribute__((ext_vector_type(4))) float f32x4;
typedef __attribute__((ext_vector_type(8))) short bf16x8;
typedef unsigned long long u64;

// part region: fast[2][B][H] | safe[2][B][H]
#define PART_WORDS (4 * B_ * H_)

// ---------------------------------------------------------------------------
// K0: invalidate all exchange tags (prev call leaves matching tags behind).
// ---------------------------------------------------------------------------
__global__ __launch_bounds__(256) void k0_init(u64* __restrict__ part) {
  const int idx = blockIdx.x * 256 + threadIdx.x;
  part[idx] = 0xFFFFFFFF00000000ull;
}

// ---------------------------------------------------------------------------
// K1: xw[bs,h] = sum_e x[bs,e] * W_ih[h,e] + b_ih[h] + b_hh[h]
// ---------------------------------------------------------------------------
__global__ __launch_bounds__(256) void k1_xw(const float* __restrict__ x,
                                             const float* __restrict__ W_ih,
                                             const float* __restrict__ b_ih,
                                             const float* __restrict__ b_hh,
                                             float* __restrict__ xw) {
  __shared__ float As[16][301];
  __shared__ float Ws[16][301];
  const int row0 = blockIdx.x * 16;
  const int col0 = blockIdx.y * 16;
  const int tid = threadIdx.x;
  for (int idx = tid; idx < 16 * E_; idx += 256) {
    int r = idx / E_, c = idx - r * E_;
    As[r][c] = x[(size_t)(row0 + r) * E_ + c];
    Ws[r][c] = W_ih[(size_t)(col0 + r) * E_ + c];
  }
  __syncthreads();
  const int i = tid >> 4, j = tid & 15;
  float acc = 0.f;
#pragma unroll 4
  for (int e = 0; e < E_; ++e) acc += As[i][e] * Ws[j][e];
  const int h = col0 + j;
  xw[(size_t)(row0 + i) * H_ + h] = acc + b_ih[h] + b_hh[h];
}

// sc1 (MALL-coherent) relaxed atomic load — always-correct path
__device__ __forceinline__ u64 pload(const u64* p) {
  return __hip_atomic_load(p, __ATOMIC_RELAXED, __HIP_MEMORY_SCOPE_AGENT);
}
// sc0 (L1-bypass, L2-point) load/store — fast path within one XCD
__device__ __forceinline__ u64 load_sc0(const u64* p) {
  u64 r;
  asm volatile("global_load_dwordx2 %0, %1, off sc0\n\ts_waitcnt vmcnt(0)"
               : "=v"(r) : "v"(p) : "memory");
  return r;
}
__device__ __forceinline__ void store_sc0(u64* p, u64 v) {
  asm volatile("global_store_dwordx2 %0, %1, off sc0" :: "v"(p), "v"(v)
               : "memory");
}
// workgroup barrier WITHOUT vmcnt drain (LDS-ordered only): store acks
// (sc0/sc1/hs) float free instead of stalling every step. The mailbox
// protocol is self-synchronizing (tag polls), so vmem needs no barrier.
__device__ __forceinline__ void lgkm_barrier() {
  asm volatile("s_waitcnt lgkmcnt(0)\n\ts_barrier" ::: "memory");
}

// ---------------------------------------------------------------------------
// K2: scan, j-split, LDS-resident W, dual-mailbox exchange (round-8 proven
// skeleton) with DEFERRED safe-publish and lgkm-only barrier.
// Block (b = blk&15, g = blk>>4) owns rows [g*32, g*32+32) of batch b; all
// 16 blocks of batch b share blk%8 = b%8 -> one XCD under round-robin
// (r8: engaged, FETCH 178->28 MB).
// Per step:
//   dot (LDS W, LDS h) -> 4-shfl reduce -> q==0: tanh + sc0 publish
//   -> BOUNDED fast poll (64 iters, sticky per-thread downgrade)
//   -> q==0: sc1 safe publish + hs store + xw prefetch   (acks drain
//      during the NEXT step; the poll above never waits on them)
//   -> if !got: spin on the sc1 word (always delivered: every publisher
//      issues it right after its BOUNDED fast poll -> inductively every
//      step's safe copy lands within bounded time; no unbounded wait on
//      a best-effort channel — the r10 hang lesson)
//   -> LDS stage -> lgkm barrier.
// Slot (t&1) reuse at distance 2 race-free: publisher reaches t+2 only
// after its poll(t+1) succeeded, which requires partners finished step t
// (consumed slot t) — argument identical for both mailboxes.
// ---------------------------------------------------------------------------
__global__ __launch_bounds__(512) void k2_scan(
    const float* __restrict__ xw, const float* __restrict__ W_hh,
    float* __restrict__ hs, u64* __restrict__ part) {
  const int b = blockIdx.x & 15;
  const int g = blockIdx.x >> 4;
  const int tid = threadIdx.x;
  const int j = tid >> 4;         // 0..31 row within slice
  const int q = tid & 15;         // k-sixteenth
  const int jg = g * JPB + j;     // global output row

  __shared__ f32x4 Wp[8 * 512];   // 64 KB, instruction-major W
  __shared__ f32x4 hp4[2][128];   // 4 KB, double-buffered h (i4-major)

  {
    const float* wrow = &W_hh[(size_t)jg * H_ + q * 32];
#pragma unroll
    for (int i4 = 0; i4 < 8; ++i4)
      Wp[i4 * 512 + tid] = *(const f32x4*)&wrow[i4 * 4];
  }
  if (tid < 128) hp4[0][tid] = (f32x4)0.f;

  u64* const fastm = part + (size_t)b * H_;             // +slot*B*H
  u64* const safem = part + (size_t)(2 * B_ + b) * H_;  // +slot*B*H
  // poll word: thread tid fills float index tid of hp4 =>
  // (i4=tid>>6, qq=(tid>>2)&15, e=tid&3) => k = qq*32 + i4*4 + e
  const int kk = ((tid >> 2) & 15) * 32 + (tid >> 6) * 4 + (tid & 3);
  bool fastok = true;

  float xwv = (q == 0) ? xw[(size_t)b * S_ * H_ + jg] : 0.f;
  __syncthreads();

  for (int t = 0; t < S_; ++t) {
    const int cur = t & 1;
    f32x4 a4 = (f32x4)0.f;
#pragma unroll
    for (int i4 = 0; i4 < 8; ++i4)
      a4 += Wp[i4 * 512 + tid] * hp4[cur][i4 * 16 + q];
    float acc = a4.x + a4.y + a4.z + a4.w;
    acc += __shfl_xor(acc, 1);
    acc += __shfl_xor(acc, 2);
    acc += __shfl_xor(acc, 4);
    acc += __shfl_xor(acc, 8);

    float hn = 0.f;
    u64 pk = 0;
    if (q == 0) {
      hn = tanhf(xwv + acc);
      pk = ((u64)(unsigned)t << 32) | (unsigned)__float_as_uint(hn);
      store_sc0(&fastm[(size_t)cur * (B_ * H_) + jg], pk);
    }
    // bounded fast poll
    u64 v = 0;
    bool got = false;
    if (t + 1 < S_ && fastok) {
      const u64* fw = &fastm[(size_t)cur * (B_ * H_) + kk];
      for (int it = 0; it < 64; ++it) {
        v = load_sc0(fw);
        if ((unsigned)(v >> 32) == (unsigned)t) { got = true; break; }
      }
      if (!got) fastok = false;  // sticky per-thread downgrade
    }
    // deferred safe publish + fire-and-forget stores (acks drain later)
    if (q == 0) {
      __hip_atomic_store(&safem[(size_t)cur * (B_ * H_) + jg], pk,
                         __ATOMIC_RELAXED, __HIP_MEMORY_SCOPE_AGENT);
      hs[((size_t)b * S_ + t) * H_ + jg] = hn;
      const int tn = (t + 1 < S_) ? t + 1 : t;
      xwv = xw[((size_t)b * S_ + tn) * H_ + jg];
    }
    if (t + 1 < S_) {
      if (!got) {
        const u64* sw = &safem[(size_t)cur * (B_ * H_) + kk];
        v = pload(sw);
        while ((unsigned)(v >> 32) != (unsigned)t) v = pload(sw);
      }
      ((float*)&hp4[cur ^ 1][0])[tid] = __uint_as_float((unsigned)v);
    }
    lgkm_barrier();
  }
}

// ---------------------------------------------------------------------------
// K5: split f32 -> bf16 hi + bf16 lo (RTN both; lo = f - hi).
// ---------------------------------------------------------------------------
__device__ __forceinline__ unsigned short bf16_rtn(float f) {
  unsigned u = __float_as_uint(f);
  return (unsigned short)((u + 0x7FFFu + ((u >> 16) & 1u)) >> 16);
}
__global__ __launch_bounds__(256) void k5_split(const float* __restrict__ src,
                                                unsigned short* __restrict__ hi,
                                                unsigned short* __restrict__ lo,
                                                int n4) {
  const int i = blockIdx.x * 256 + threadIdx.x;
  if (i >= n4) return;
  const float4 f = *(const float4*)&src[i * 4];
  unsigned short h[4], l[4];
  const float ff[4] = {f.x, f.y, f.z, f.w};
#pragma unroll
  for (int k = 0; k < 4; ++k) {
    h[k] = bf16_rtn(ff[k]);
    const float fh = __uint_as_float((unsigned)h[k] << 16);
    l[k] = bf16_rtn(ff[k] - fh);
  }
  *(ushort4*)&hi[i * 4] = make_ushort4(h[0], h[1], h[2], h[3]);
  *(ushort4*)&lo[i * 4] = make_ushort4(l[0], l[1], l[2], l[3]);
}

// ---------------------------------------------------------------------------
// K3: logits = hs @ W_fc^T + b_fc, bf16 hi/lo split MFMA (hh+hl+lh).
// m97-style staging: global_load_lds width-16, linear [128][32]-bf16 tiles,
// XOR chunk-swizzle (chunk ^= row&3) on pre-swizzled global src + ds_read.
// ---------------------------------------------------------------------------
__global__ __launch_bounds__(256) void k3_logits(
    const unsigned short* __restrict__ Ahi, const unsigned short* __restrict__ Alo,
    const unsigned short* __restrict__ Bhi, const unsigned short* __restrict__ Blo,
    const float* __restrict__ b_fc, float* __restrict__ out) {
  __shared__ unsigned short Ah[128 * 32], Al[128 * 32];
  __shared__ unsigned short Bh[128 * 32], Bl[128 * 32];
  const int m0 = blockIdx.x * 128;
  const int n0 = blockIdx.y * 128;
  const int tid = threadIdx.x;
  const int lane = tid & 63;
  const int wave = tid >> 6;
  const int wm = wave >> 1, wn = wave & 1;
  const int lr = lane & 15;
  const int cxr = ((lane >> 4) ^ (lr & 3)) * 8;  // swizzled k-chunk (shorts)

  const unsigned short* gp = (wave == 0) ? Ahi : (wave == 1) ? Alo
                           : (wave == 2) ? Bhi : Blo;
  unsigned short* lp = (wave == 0) ? Ah : (wave == 1) ? Al
                     : (wave == 2) ? Bh : Bl;
  const bool isB = wave >= 2;
  const int lrow = lane >> 2;
  const int lchunk = (lane & 3) ^ (lrow & 3);

  f32x4 acc[4][4];
#pragma unroll
  for (int mi = 0; mi < 4; ++mi)
#pragma unroll
    for (int ni = 0; ni < 4; ++ni) acc[mi][ni] = (f32x4)0.0f;

  for (int k0 = 0; k0 < H_; k0 += 32) {
    __syncthreads();
#pragma unroll
    for (int c16 = 0; c16 < 8; ++c16) {
      const int r = c16 * 16 + lrow;
      const int grow = isB ? min(n0 + r, V_ - 1) : (m0 + r);
      const unsigned short* src = gp + (size_t)grow * H_ + k0 + lchunk * 8;
      __builtin_amdgcn_global_load_lds(
          (const __attribute__((address_space(1))) void*)src,
          (__attribute__((address_space(3))) void*)(lp + c16 * 512), 16, 0, 0);
    }
    __syncthreads();

    bf16x8 ah[4], al[4], bh[4], bl[4];
#pragma unroll
    for (int i = 0; i < 4; ++i) {
      ah[i] = *(const bf16x8*)&Ah[(wm * 64 + i * 16 + lr) * 32 + cxr];
      al[i] = *(const bf16x8*)&Al[(wm * 64 + i * 16 + lr) * 32 + cxr];
      bh[i] = *(const bf16x8*)&Bh[(wn * 64 + i * 16 + lr) * 32 + cxr];
      bl[i] = *(const bf16x8*)&Bl[(wn * 64 + i * 16 + lr) * 32 + cxr];
    }
#pragma unroll
    for (int mi = 0; mi < 4; ++mi)
#pragma unroll
      for (int ni = 0; ni < 4; ++ni) {
        acc[mi][ni] = __builtin_amdgcn_mfma_f32_16x16x32_bf16(
            ah[mi], bh[ni], acc[mi][ni], 0, 0, 0);
        acc[mi][ni] = __builtin_amdgcn_mfma_f32_16x16x32_bf16(
            ah[mi], bl[ni], acc[mi][ni], 0, 0, 0);
        acc[mi][ni] = __builtin_amdgcn_mfma_f32_16x16x32_bf16(
            al[mi], bh[ni], acc[mi][ni], 0, 0, 0);
      }
  }

#pragma unroll
  for (int ni = 0; ni < 4; ++ni) {
    const int v = n0 + wn * 64 + ni * 16 + lr;
    if (v >= V_) continue;
    const float bias = b_fc[v];
#pragma unroll
    for (int mi = 0; mi < 4; ++mi) {
      const int mrow = m0 + wm * 64 + mi * 16 + (lane >> 4) * 4;
#pragma unroll
      for (int r = 0; r < 4; ++r)
        out[(size_t)(mrow + r) * V_ + v] = acc[mi][ni][r] + bias;
    }
  }
}

// ---------------------------------------------------------------------------
// K4a: per-(b,v) online max+sum over S; 4-wide s-unroll (4 independent
// loads in flight per iter — the loop was latency-bound at 1 load deep).
// Branchless merge: nm = max(m, max4); sum = sum*e^(m-nm) + sum of e^(xi-nm).
// ---------------------------------------------------------------------------
__global__ __launch_bounds__(256) void k4_stats(const float* __restrict__ logits,
                                                float* __restrict__ stats) {
  const int gg = blockIdx.x * 256 + threadIdx.x;
  const int b = gg / V_;
  const int v = gg - b * V_;
  const float* p = logits + (size_t)b * S_ * V_ + v;
  float m = -3.4e38f, sum = 0.f;
  for (int s = 0; s < S_; s += 4) {
    const float x0 = p[(size_t)(s + 0) * V_];
    const float x1 = p[(size_t)(s + 1) * V_];
    const float x2 = p[(size_t)(s + 2) * V_];
    const float x3 = p[(size_t)(s + 3) * V_];
    const float m4 = fmaxf(fmaxf(x0, x1), fmaxf(x2, x3));
    const float nm = fmaxf(m, m4);
    sum = sum * __expf(m - nm) + __expf(x0 - nm) + __expf(x1 - nm) +
          __expf(x2 - nm) + __expf(x3 - nm);
    m = nm;
  }
  stats[2 * gg] = m;
  stats[2 * gg + 1] = 1.f / sum;
}

// ---------------------------------------------------------------------------
// K4b: normalize, float4, no int-div: grid (ceil(V/1024), BS).
// ---------------------------------------------------------------------------
__global__ __launch_bounds__(256) void k4_norm(float* __restrict__ logits,
                                               const float* __restrict__ stats) {
  const int bs = blockIdx.y;
  const int b = bs >> 9;
  const int v0 = blockIdx.x * 1024 + threadIdx.x * 4;
  if (v0 >= V_) return;
  float* p = logits + (size_t)bs * V_ + v0;
  const float4 l = *(const float4*)p;
  const float4 s01 = *(const float4*)&stats[2 * (b * V_ + v0)];
  const float4 s23 = *(const float4*)&stats[2 * (b * V_ + v0) + 4];
  float4 o;
  o.x = __expf(l.x - s01.x) * s01.y;
  o.y = __expf(l.y - s01.z) * s01.w;
  o.z = __expf(l.z - s23.x) * s23.y;
  o.w = __expf(l.w - s23.z) * s23.w;
  *(float4*)p = o;
}

extern "C" void kernel_launch(void* const* d_in, const int* in_sizes, int n_in,
                              void* d_out, int out_size, void* d_ws,
                              size_t ws_size, hipStream_t stream) {
  const float* x    = (const float*)d_in[0];
  const float* W_ih = (const float*)d_in[1];
  const float* W_hh = (const float*)d_in[2];
  const float* b_ih = (const float*)d_in[3];
  const float* b_hh = (const float*)d_in[4];
  const float* W_fc = (const float*)d_in[5];
  const float* b_fc = (const float*)d_in[6];
  float* out = (float*)d_out;

  // ws layout (floats): xw | hs | stats | wfc_hi | wfc_lo
  //   part (256 KB, scan-only) ALIASES wfc_hi (k2 done before k5_wfc)
  //   hs_hi/hs_lo (bf16) ALIAS xw (dead after k2)
  float* ws = (float*)d_ws;
  float* xw    = ws;
  float* hs    = xw + (size_t)BS_ * H_;
  float* stats = hs + (size_t)BS_ * H_;
  unsigned short* wfc_hi = (unsigned short*)(stats + (size_t)2 * B_ * V_);
  unsigned short* wfc_lo = wfc_hi + (size_t)V_ * H_;
  u64* part = (u64*)wfc_hi;
  unsigned short* hs_hi = (unsigned short*)xw;
  unsigned short* hs_lo = hs_hi + (size_t)BS_ * H_;

  k0_init<<<PART_WORDS / 256, 256, 0, stream>>>(part);
  k1_xw<<<dim3(BS_ / 16, H_ / 16), 256, 0, stream>>>(x, W_ih, b_ih, b_hh, xw);
  k2_scan<<<NBLK, 512, 0, stream>>>(xw, W_hh, hs, part);
  k5_split<<<((V_ * H_ / 4) + 255) / 256, 256, 0, stream>>>(W_fc, wfc_hi,
                                                            wfc_lo, V_ * H_ / 4);
  k5_split<<<((BS_ * H_ / 4) + 255) / 256, 256, 0, stream>>>(
      hs, hs_hi, hs_lo, BS_ * H_ / 4);
  k3_logits<<<dim3(BS_ / 128, (V_ + 127) / 128), 256, 0, stream>>>(
      hs_hi, hs_lo, wfc_hi, wfc_lo, b_fc, out);
  k4_stats<<<(B_ * V_) / 256, 256, 0, stream>>>(out, stats);
  k4_norm<<<dim3((V_ + 1023) / 1024, BS_), 256, 0, stream>>>(out, stats);
}

// Round 12
// 1417.166 us; speedup vs baseline: 1.9096x; 1.9096x over previous
//
#include <hip/hip_runtime.h>
#include <hip/hip_bf16.h>
#include <math.h>

#define B_ 16
#define S_ 512
#define E_ 300
#define H_ 512
#define V_ 10000
#define BS_ (B_ * S_)  // 8192

#define NSL 16           // slices (blocks) per batch, j-split
#define JPB (H_ / NSL)   // 32 output rows per block
#define NBLK (B_ * NSL)  // 256 blocks in the scan

typedef __attribute__((ext_vector_type(4))) float f32x4;
typedef __attribute__((ext_vector_type(8))) short bf16x8;
typedef unsigned long long u64;

// part region: fast[2][B][H] | safe[2][B][H]
#define PART_WORDS (4 * B_ * H_)

// ---------------------------------------------------------------------------
// K0: invalidate exchange tags in BOTH mailboxes (prev call leaves tags
// 0..511 that would falsely match).
// ---------------------------------------------------------------------------
__global__ __launch_bounds__(256) void k0_init(u64* __restrict__ part) {
  const int idx = blockIdx.x * 256 + threadIdx.x;
  part[idx] = 0xFFFFFFFF00000000ull;
}

// ---------------------------------------------------------------------------
// K1: xw[bs,h] = sum_e x[bs,e] * W_ih[h,e] + b_ih[h] + b_hh[h]
// ---------------------------------------------------------------------------
__global__ __launch_bounds__(256) void k1_xw(const float* __restrict__ x,
                                             const float* __restrict__ W_ih,
                                             const float* __restrict__ b_ih,
                                             const float* __restrict__ b_hh,
                                             float* __restrict__ xw) {
  __shared__ float As[16][301];
  __shared__ float Ws[16][301];
  const int row0 = blockIdx.x * 16;
  const int col0 = blockIdx.y * 16;
  const int tid = threadIdx.x;
  for (int idx = tid; idx < 16 * E_; idx += 256) {
    int r = idx / E_, c = idx - r * E_;
    As[r][c] = x[(size_t)(row0 + r) * E_ + c];
    Ws[r][c] = W_ih[(size_t)(col0 + r) * E_ + c];
  }
  __syncthreads();
  const int i = tid >> 4, j = tid & 15;
  float acc = 0.f;
#pragma unroll 4
  for (int e = 0; e < E_; ++e) acc += As[i][e] * Ws[j][e];
  const int h = col0 + j;
  xw[(size_t)(row0 + i) * H_ + h] = acc + b_ih[h] + b_hh[h];
}

// sc1 (MALL-coherent) relaxed atomic load — always-correct path
__device__ __forceinline__ u64 pload(const u64* p) {
  return __hip_atomic_load(p, __ATOMIC_RELAXED, __HIP_MEMORY_SCOPE_AGENT);
}
// sc0 (L1-bypass, L2-point) load/store — fast path within one XCD
__device__ __forceinline__ u64 load_sc0(const u64* p) {
  u64 r;
  asm volatile("global_load_dwordx2 %0, %1, off sc0\n\ts_waitcnt vmcnt(0)"
               : "=v"(r) : "v"(p) : "memory");
  return r;
}
__device__ __forceinline__ void store_sc0(u64* p, u64 v) {
  asm volatile("global_store_dwordx2 %0, %1, off sc0" :: "v"(p), "v"(v)
               : "memory");
}

// ---------------------------------------------------------------------------
// K2: scan — ROUND-8 VERBATIM (measured 689 us, FETCH 28 MB). Every
// deviation tried since regressed: r9 dual-batch 1650 (serialized compute),
// r10 unbounded fast spin (hang), r11 deferred sc1 publish 1970 (poisoned
// fallback latency). Protocol: j-split, LDS-resident instruction-major W;
// publisher (q==0) writes tagged u64 (t<<32|f32(h)) to fast (sc0/XCD-L2)
// AND safe (sc1/MALL) mailboxes BEFORE any poll; consumers poll fast with
// a 64-iter bound and a sticky per-thread downgrade to the always-delivered
// safe word. Slot (t&1) reuse at distance 2 race-free.
// ---------------------------------------------------------------------------
__global__ __launch_bounds__(512) void k2_scan(
    const float* __restrict__ xw, const float* __restrict__ W_hh,
    float* __restrict__ hs, u64* __restrict__ part) {
  const int b = blockIdx.x & 15;  // batch -> XCD b%8 under round-robin
  const int g = blockIdx.x >> 4;  // slice
  const int tid = threadIdx.x;
  const int j = tid >> 4;         // 0..31 row within slice
  const int q = tid & 15;         // k-sixteenth
  const int jg = g * JPB + j;     // global output row

  __shared__ f32x4 Wp[8 * 512];   // 64 KB, instruction-major W
  __shared__ f32x4 hp4[2][128];   // 4 KB, double-buffered h (i4-major)

  {
    const float* wrow = &W_hh[(size_t)jg * H_ + q * 32];
#pragma unroll
    for (int i4 = 0; i4 < 8; ++i4)
      Wp[i4 * 512 + tid] = *(const f32x4*)&wrow[i4 * 4];
  }
  if (tid < 128) hp4[0][tid] = (f32x4)0.f;

  u64* const pf = part + (size_t)b * H_;             // +slot*B*H
  u64* const ps = part + (size_t)(2 * B_ + b) * H_;  // +slot*B*H
  // poll word: thread tid fills float index tid of hp4 =>
  // (i4=tid>>6, qq=(tid>>2)&15, e=tid&3) => k = qq*32 + i4*4 + e
  const int kk = ((tid & 63) >> 2) * 32 + (tid >> 6) * 4 + (tid & 3);
  bool fast = true;

  float xwv = xw[(size_t)b * S_ * H_ + jg];  // t = 0
  __syncthreads();

  for (int t = 0; t < S_; ++t) {
    const int cur = t & 1;
    // dot: 8 x (b128 W read, b128 h broadcast, fma4)
    f32x4 a4 = (f32x4)0.f;
#pragma unroll
    for (int i4 = 0; i4 < 8; ++i4) {
      const f32x4 wv = Wp[i4 * 512 + tid];
      const f32x4 hv = hp4[cur][i4 * 16 + q];
      a4 += wv * hv;
    }
    float acc = a4.x + a4.y + a4.z + a4.w;
    acc += __shfl_xor(acc, 1);
    acc += __shfl_xor(acc, 2);
    acc += __shfl_xor(acc, 4);
    acc += __shfl_xor(acc, 8);

    if (q == 0) {
      const float hn = tanhf(xwv + acc);
      const u64 pk =
          ((u64)(unsigned)t << 32) | (u64)(unsigned)__float_as_uint(hn);
      store_sc0(&pf[(size_t)cur * (B_ * H_) + jg], pk);
      __hip_atomic_store(&ps[(size_t)cur * (B_ * H_) + jg], pk,
                         __ATOMIC_RELAXED, __HIP_MEMORY_SCOPE_AGENT);
      hs[((size_t)b * S_ + t) * H_ + jg] = hn;
    }
    // prefetch next xw while partners compute/publish
    const int tn = (t + 1 < S_) ? t + 1 : t;
    const float xw_next = xw[((size_t)b * S_ + tn) * H_ + jg];

    if (t + 1 < S_) {
      u64 v = 0;
      bool got = false;
      const u64* fw = &pf[(size_t)cur * (B_ * H_) + kk];
      if (fast) {
        for (int it = 0; it < 64; ++it) {
          v = load_sc0(fw);
          if ((unsigned)(v >> 32) == (unsigned)t) { got = true; break; }
        }
        if (!got) fast = false;  // sticky downgrade (cross-XCD placement)
      }
      if (!got) {
        const u64* sw = &ps[(size_t)cur * (B_ * H_) + kk];
        v = pload(sw);
        while ((unsigned)(v >> 32) != (unsigned)t) v = pload(sw);
      }
      ((float*)&hp4[cur ^ 1][0])[tid] = __uint_as_float((unsigned)v);
    }
    xwv = xw_next;
    __syncthreads();
  }
}

// ---------------------------------------------------------------------------
// K5: split f32 -> bf16 hi + bf16 lo (RTN both; lo = f - hi).
// ---------------------------------------------------------------------------
__device__ __forceinline__ unsigned short bf16_rtn(float f) {
  unsigned u = __float_as_uint(f);
  return (unsigned short)((u + 0x7FFFu + ((u >> 16) & 1u)) >> 16);
}
__global__ __launch_bounds__(256) void k5_split(const float* __restrict__ src,
                                                unsigned short* __restrict__ hi,
                                                unsigned short* __restrict__ lo,
                                                int n4) {
  const int i = blockIdx.x * 256 + threadIdx.x;
  if (i >= n4) return;
  const float4 f = *(const float4*)&src[i * 4];
  unsigned short h[4], l[4];
  const float ff[4] = {f.x, f.y, f.z, f.w};
#pragma unroll
  for (int k = 0; k < 4; ++k) {
    h[k] = bf16_rtn(ff[k]);
    const float fh = __uint_as_float((unsigned)h[k] << 16);
    l[k] = bf16_rtn(ff[k] - fh);
  }
  *(ushort4*)&hi[i * 4] = make_ushort4(h[0], h[1], h[2], h[3]);
  *(ushort4*)&lo[i * 4] = make_ushort4(l[0], l[1], l[2], l[3]);
}

// ---------------------------------------------------------------------------
// K3: logits = hs @ W_fc^T + b_fc, bf16 hi/lo split MFMA (hh+hl+lh).
// m97-style staging: global_load_lds width-16, linear [128][32]-bf16 tiles,
// XOR chunk-swizzle (chunk ^= row&3) on pre-swizzled global src + ds_read.
// ---------------------------------------------------------------------------
__global__ __launch_bounds__(256) void k3_logits(
    const unsigned short* __restrict__ Ahi, const unsigned short* __restrict__ Alo,
    const unsigned short* __restrict__ Bhi, const unsigned short* __restrict__ Blo,
    const float* __restrict__ b_fc, float* __restrict__ out) {
  __shared__ unsigned short Ah[128 * 32], Al[128 * 32];
  __shared__ unsigned short Bh[128 * 32], Bl[128 * 32];
  const int m0 = blockIdx.x * 128;
  const int n0 = blockIdx.y * 128;
  const int tid = threadIdx.x;
  const int lane = tid & 63;
  const int wave = tid >> 6;
  const int wm = wave >> 1, wn = wave & 1;
  const int lr = lane & 15;
  const int cxr = ((lane >> 4) ^ (lr & 3)) * 8;  // swizzled k-chunk (shorts)

  const unsigned short* gp = (wave == 0) ? Ahi : (wave == 1) ? Alo
                           : (wave == 2) ? Bhi : Blo;
  unsigned short* lp = (wave == 0) ? Ah : (wave == 1) ? Al
                     : (wave == 2) ? Bh : Bl;
  const bool isB = wave >= 2;
  const int lrow = lane >> 2;
  const int lchunk = (lane & 3) ^ (lrow & 3);

  f32x4 acc[4][4];
#pragma unroll
  for (int mi = 0; mi < 4; ++mi)
#pragma unroll
    for (int ni = 0; ni < 4; ++ni) acc[mi][ni] = (f32x4)0.0f;

  for (int k0 = 0; k0 < H_; k0 += 32) {
    __syncthreads();
#pragma unroll
    for (int c16 = 0; c16 < 8; ++c16) {
      const int r = c16 * 16 + lrow;
      const int grow = isB ? min(n0 + r, V_ - 1) : (m0 + r);
      const unsigned short* src = gp + (size_t)grow * H_ + k0 + lchunk * 8;
      __builtin_amdgcn_global_load_lds(
          (const __attribute__((address_space(1))) void*)src,
          (__attribute__((address_space(3))) void*)(lp + c16 * 512), 16, 0, 0);
    }
    __syncthreads();

    bf16x8 ah[4], al[4], bh[4], bl[4];
#pragma unroll
    for (int i = 0; i < 4; ++i) {
      ah[i] = *(const bf16x8*)&Ah[(wm * 64 + i * 16 + lr) * 32 + cxr];
      al[i] = *(const bf16x8*)&Al[(wm * 64 + i * 16 + lr) * 32 + cxr];
      bh[i] = *(const bf16x8*)&Bh[(wn * 64 + i * 16 + lr) * 32 + cxr];
      bl[i] = *(const bf16x8*)&Bl[(wn * 64 + i * 16 + lr) * 32 + cxr];
    }
#pragma unroll
    for (int mi = 0; mi < 4; ++mi)
#pragma unroll
      for (int ni = 0; ni < 4; ++ni) {
        acc[mi][ni] = __builtin_amdgcn_mfma_f32_16x16x32_bf16(
            ah[mi], bh[ni], acc[mi][ni], 0, 0, 0);
        acc[mi][ni] = __builtin_amdgcn_mfma_f32_16x16x32_bf16(
            ah[mi], bl[ni], acc[mi][ni], 0, 0, 0);
        acc[mi][ni] = __builtin_amdgcn_mfma_f32_16x16x32_bf16(
            al[mi], bh[ni], acc[mi][ni], 0, 0, 0);
      }
  }

#pragma unroll
  for (int ni = 0; ni < 4; ++ni) {
    const int v = n0 + wn * 64 + ni * 16 + lr;
    if (v >= V_) continue;
    const float bias = b_fc[v];
#pragma unroll
    for (int mi = 0; mi < 4; ++mi) {
      const int mrow = m0 + wm * 64 + mi * 16 + (lane >> 4) * 4;
#pragma unroll
      for (int r = 0; r < 4; ++r)
        out[(size_t)(mrow + r) * V_ + v] = acc[mi][ni][r] + bias;
    }
  }
}

// ---------------------------------------------------------------------------
// K4a: per-(b,v) online max+sum over S; 4-wide s-unroll (4 independent
// loads in flight — the 1-deep loop was latency-bound). Branchless merge.
// ---------------------------------------------------------------------------
__global__ __launch_bounds__(256) void k4_stats(const float* __restrict__ logits,
                                                float* __restrict__ stats) {
  const int gg = blockIdx.x * 256 + threadIdx.x;
  const int b = gg / V_;
  const int v = gg - b * V_;
  const float* p = logits + (size_t)b * S_ * V_ + v;
  float m = -3.4e38f, sum = 0.f;
  for (int s = 0; s < S_; s += 4) {
    const float x0 = p[(size_t)(s + 0) * V_];
    const float x1 = p[(size_t)(s + 1) * V_];
    const float x2 = p[(size_t)(s + 2) * V_];
    const float x3 = p[(size_t)(s + 3) * V_];
    const float m4 = fmaxf(fmaxf(x0, x1), fmaxf(x2, x3));
    const float nm = fmaxf(m, m4);
    sum = sum * __expf(m - nm) + __expf(x0 - nm) + __expf(x1 - nm) +
          __expf(x2 - nm) + __expf(x3 - nm);
    m = nm;
  }
  stats[2 * gg] = m;
  stats[2 * gg + 1] = 1.f / sum;
}

// ---------------------------------------------------------------------------
// K4b: normalize, float4, no int-div: grid (ceil(V/1024), BS).
// ---------------------------------------------------------------------------
__global__ __launch_bounds__(256) void k4_norm(float* __restrict__ logits,
                                               const float* __restrict__ stats) {
  const int bs = blockIdx.y;
  const int b = bs >> 9;
  const int v0 = blockIdx.x * 1024 + threadIdx.x * 4;
  if (v0 >= V_) return;
  float* p = logits + (size_t)bs * V_ + v0;
  const float4 l = *(const float4*)p;
  const float4 s01 = *(const float4*)&stats[2 * (b * V_ + v0)];
  const float4 s23 = *(const float4*)&stats[2 * (b * V_ + v0) + 4];
  float4 o;
  o.x = __expf(l.x - s01.x) * s01.y;
  o.y = __expf(l.y - s01.z) * s01.w;
  o.z = __expf(l.z - s23.x) * s23.y;
  o.w = __expf(l.w - s23.z) * s23.w;
  *(float4*)p = o;
}

extern "C" void kernel_launch(void* const* d_in, const int* in_sizes, int n_in,
                              void* d_out, int out_size, void* d_ws,
                              size_t ws_size, hipStream_t stream) {
  const float* x    = (const float*)d_in[0];
  const float* W_ih = (const float*)d_in[1];
  const float* W_hh = (const float*)d_in[2];
  const float* b_ih = (const float*)d_in[3];
  const float* b_hh = (const float*)d_in[4];
  const float* W_fc = (const float*)d_in[5];
  const float* b_fc = (const float*)d_in[6];
  float* out = (float*)d_out;

  // ws layout (floats): xw | hs | stats | wfc_hi | wfc_lo
  //   part (256 KB, scan-only) ALIASES wfc_hi (k2 done before k5_wfc)
  //   hs_hi/hs_lo (bf16) ALIAS xw (dead after k2)
  float* ws = (float*)d_ws;
  float* xw    = ws;
  float* hs    = xw + (size_t)BS_ * H_;
  float* stats = hs + (size_t)BS_ * H_;
  unsigned short* wfc_hi = (unsigned short*)(stats + (size_t)2 * B_ * V_);
  unsigned short* wfc_lo = wfc_hi + (size_t)V_ * H_;
  u64* part = (u64*)wfc_hi;
  unsigned short* hs_hi = (unsigned short*)xw;
  unsigned short* hs_lo = hs_hi + (size_t)BS_ * H_;

  k0_init<<<PART_WORDS / 256, 256, 0, stream>>>(part);
  k1_xw<<<dim3(BS_ / 16, H_ / 16), 256, 0, stream>>>(x, W_ih, b_ih, b_hh, xw);
  k2_scan<<<NBLK, 512, 0, stream>>>(xw, W_hh, hs, part);
  k5_split<<<((V_ * H_ / 4) + 255) / 256, 256, 0, stream>>>(W_fc, wfc_hi,
                                                            wfc_lo, V_ * H_ / 4);
  k5_split<<<((BS_ * H_ / 4) + 255) / 256, 256, 0, stream>>>(
      hs, hs_hi, hs_lo, BS_ * H_ / 4);
  k3_logits<<<dim3(BS_ / 128, (V_ + 127) / 128), 256, 0, stream>>>(
      hs_hi, hs_lo, wfc_hi, wfc_lo, b_fc, out);
  k4_stats<<<(B_ * V_) / 256, 256, 0, stream>>>(out, stats);
  k4_norm<<<dim3((V_ + 1023) / 1024, BS_), 256, 0, stream>>>(out, stats);
}

// Round 13
// 1373.301 us; speedup vs baseline: 1.9705x; 1.0319x over previous
//
#include <hip/hip_runtime.h>
#include <hip/hip_bf16.h>
#include <math.h>

#define B_ 16
#define S_ 512
#define E_ 300
#define H_ 512
#define V_ 10000
#define BS_ (B_ * S_)  // 8192

#define NSL 16           // slices (blocks) per batch, j-split
#define JPB (H_ / NSL)   // 32 output rows per block
#define NBLK (B_ * NSL)  // 256 blocks in the scan

typedef __attribute__((ext_vector_type(4))) float f32x4;
typedef __attribute__((ext_vector_type(8))) short bf16x8;
typedef unsigned long long u64;

// part region: fast[2][B][H] | safe[2][B][H]
#define PART_WORDS (4 * B_ * H_)

// ---------------------------------------------------------------------------
// K0: invalidate exchange tags in BOTH mailboxes (prev call leaves tags
// 0..511 that would falsely match).
// ---------------------------------------------------------------------------
__global__ __launch_bounds__(256) void k0_init(u64* __restrict__ part) {
  const int idx = blockIdx.x * 256 + threadIdx.x;
  part[idx] = 0xFFFFFFFF00000000ull;
}

// ---------------------------------------------------------------------------
// K1: xw[bs,h] = sum_e x[bs,e] * W_ih[h,e] + b_ih[h] + b_hh[h]
// ---------------------------------------------------------------------------
__global__ __launch_bounds__(256) void k1_xw(const float* __restrict__ x,
                                             const float* __restrict__ W_ih,
                                             const float* __restrict__ b_ih,
                                             const float* __restrict__ b_hh,
                                             float* __restrict__ xw) {
  __shared__ float As[16][301];
  __shared__ float Ws[16][301];
  const int row0 = blockIdx.x * 16;
  const int col0 = blockIdx.y * 16;
  const int tid = threadIdx.x;
  for (int idx = tid; idx < 16 * E_; idx += 256) {
    int r = idx / E_, c = idx - r * E_;
    As[r][c] = x[(size_t)(row0 + r) * E_ + c];
    Ws[r][c] = W_ih[(size_t)(col0 + r) * E_ + c];
  }
  __syncthreads();
  const int i = tid >> 4, j = tid & 15;
  float acc = 0.f;
#pragma unroll 4
  for (int e = 0; e < E_; ++e) acc += As[i][e] * Ws[j][e];
  const int h = col0 + j;
  xw[(size_t)(row0 + i) * H_ + h] = acc + b_ih[h] + b_hh[h];
}

// sc1 (MALL-coherent) relaxed atomic load — always-correct path
__device__ __forceinline__ u64 pload(const u64* p) {
  return __hip_atomic_load(p, __ATOMIC_RELAXED, __HIP_MEMORY_SCOPE_AGENT);
}
// sc0 (L1-bypass, L2-point) load/store — fast path within one XCD
__device__ __forceinline__ u64 load_sc0(const u64* p) {
  u64 r;
  asm volatile("global_load_dwordx2 %0, %1, off sc0\n\ts_waitcnt vmcnt(0)"
               : "=v"(r) : "v"(p) : "memory");
  return r;
}
__device__ __forceinline__ void store_sc0(u64* p, u64 v) {
  asm volatile("global_store_dwordx2 %0, %1, off sc0" :: "v"(p), "v"(v)
               : "memory");
}

// ---------------------------------------------------------------------------
// K2: scan — ROUND-8 VERBATIM (banked: r12 re-measured 692 us, FETCH 28 MB).
// Deviations that regressed: r9 dual-batch 1650 (serialized compute), r10
// unbounded fast spin (hang), r11 deferred sc1 publish 1970 (poisoned
// fallback). DO NOT MODIFY without a bounded, revertible experiment.
// ---------------------------------------------------------------------------
__global__ __launch_bounds__(512) void k2_scan(
    const float* __restrict__ xw, const float* __restrict__ W_hh,
    float* __restrict__ hs, u64* __restrict__ part) {
  const int b = blockIdx.x & 15;  // batch -> XCD b%8 under round-robin
  const int g = blockIdx.x >> 4;  // slice
  const int tid = threadIdx.x;
  const int j = tid >> 4;         // 0..31 row within slice
  const int q = tid & 15;         // k-sixteenth
  const int jg = g * JPB + j;     // global output row

  __shared__ f32x4 Wp[8 * 512];   // 64 KB, instruction-major W
  __shared__ f32x4 hp4[2][128];   // 4 KB, double-buffered h (i4-major)

  {
    const float* wrow = &W_hh[(size_t)jg * H_ + q * 32];
#pragma unroll
    for (int i4 = 0; i4 < 8; ++i4)
      Wp[i4 * 512 + tid] = *(const f32x4*)&wrow[i4 * 4];
  }
  if (tid < 128) hp4[0][tid] = (f32x4)0.f;

  u64* const pf = part + (size_t)b * H_;             // +slot*B*H
  u64* const ps = part + (size_t)(2 * B_ + b) * H_;  // +slot*B*H
  const int kk = ((tid & 63) >> 2) * 32 + (tid >> 6) * 4 + (tid & 3);
  bool fast = true;

  float xwv = xw[(size_t)b * S_ * H_ + jg];  // t = 0
  __syncthreads();

  for (int t = 0; t < S_; ++t) {
    const int cur = t & 1;
    f32x4 a4 = (f32x4)0.f;
#pragma unroll
    for (int i4 = 0; i4 < 8; ++i4) {
      const f32x4 wv = Wp[i4 * 512 + tid];
      const f32x4 hv = hp4[cur][i4 * 16 + q];
      a4 += wv * hv;
    }
    float acc = a4.x + a4.y + a4.z + a4.w;
    acc += __shfl_xor(acc, 1);
    acc += __shfl_xor(acc, 2);
    acc += __shfl_xor(acc, 4);
    acc += __shfl_xor(acc, 8);

    if (q == 0) {
      const float hn = tanhf(xwv + acc);
      const u64 pk =
          ((u64)(unsigned)t << 32) | (u64)(unsigned)__float_as_uint(hn);
      store_sc0(&pf[(size_t)cur * (B_ * H_) + jg], pk);
      __hip_atomic_store(&ps[(size_t)cur * (B_ * H_) + jg], pk,
                         __ATOMIC_RELAXED, __HIP_MEMORY_SCOPE_AGENT);
      hs[((size_t)b * S_ + t) * H_ + jg] = hn;
    }
    const int tn = (t + 1 < S_) ? t + 1 : t;
    const float xw_next = xw[((size_t)b * S_ + tn) * H_ + jg];

    if (t + 1 < S_) {
      u64 v = 0;
      bool got = false;
      const u64* fw = &pf[(size_t)cur * (B_ * H_) + kk];
      if (fast) {
        for (int it = 0; it < 64; ++it) {
          v = load_sc0(fw);
          if ((unsigned)(v >> 32) == (unsigned)t) { got = true; break; }
        }
        if (!got) fast = false;  // sticky downgrade (cross-XCD placement)
      }
      if (!got) {
        const u64* sw = &ps[(size_t)cur * (B_ * H_) + kk];
        v = pload(sw);
        while ((unsigned)(v >> 32) != (unsigned)t) v = pload(sw);
      }
      ((float*)&hp4[cur ^ 1][0])[tid] = __uint_as_float((unsigned)v);
    }
    xwv = xw_next;
    __syncthreads();
  }
}

// ---------------------------------------------------------------------------
// K5: split f32 -> bf16 hi + bf16 lo (RTN both; lo = f - hi).
// ---------------------------------------------------------------------------
__device__ __forceinline__ unsigned short bf16_rtn(float f) {
  unsigned u = __float_as_uint(f);
  return (unsigned short)((u + 0x7FFFu + ((u >> 16) & 1u)) >> 16);
}
__global__ __launch_bounds__(256) void k5_split(const float* __restrict__ src,
                                                unsigned short* __restrict__ hi,
                                                unsigned short* __restrict__ lo,
                                                int n4) {
  const int i = blockIdx.x * 256 + threadIdx.x;
  if (i >= n4) return;
  const float4 f = *(const float4*)&src[i * 4];
  unsigned short h[4], l[4];
  const float ff[4] = {f.x, f.y, f.z, f.w};
#pragma unroll
  for (int k = 0; k < 4; ++k) {
    h[k] = bf16_rtn(ff[k]);
    const float fh = __uint_as_float((unsigned)h[k] << 16);
    l[k] = bf16_rtn(ff[k] - fh);
  }
  *(ushort4*)&hi[i * 4] = make_ushort4(h[0], h[1], h[2], h[3]);
  *(ushort4*)&lo[i * 4] = make_ushort4(l[0], l[1], l[2], l[3]);
}

// ---------------------------------------------------------------------------
// K3: logits = hs @ W_fc^T + b_fc, bf16 hi/lo split MFMA (hh+hl+lh), PLUS
// fused per-block softmax partials: each block's 128 rows lie inside one
// batch (512/128=4), so it reduces its in-register logits to (max, sum-exp)
// per column and stores pstats[m_block][v] — k4a's 327 MB column-strided
// re-read becomes a 10 MB partial merge.
// ---------------------------------------------------------------------------
__global__ __launch_bounds__(256) void k3_logits(
    const unsigned short* __restrict__ Ahi, const unsigned short* __restrict__ Alo,
    const unsigned short* __restrict__ Bhi, const unsigned short* __restrict__ Blo,
    const float* __restrict__ b_fc, float* __restrict__ out,
    float2* __restrict__ pstats) {
  __shared__ unsigned short Ah[128 * 32], Al[128 * 32];
  __shared__ unsigned short Bh[128 * 32], Bl[128 * 32];
  __shared__ float2 sstat[2][2][4][16];  // [wm][wn][ni][lr]
  const int m0 = blockIdx.x * 128;
  const int n0 = blockIdx.y * 128;
  const int tid = threadIdx.x;
  const int lane = tid & 63;
  const int wave = tid >> 6;
  const int wm = wave >> 1, wn = wave & 1;
  const int lr = lane & 15;
  const int lg = lane >> 4;
  const int cxr = (lg ^ (lr & 3)) * 8;  // swizzled k-chunk (shorts)

  const unsigned short* gp = (wave == 0) ? Ahi : (wave == 1) ? Alo
                           : (wave == 2) ? Bhi : Blo;
  unsigned short* lp = (wave == 0) ? Ah : (wave == 1) ? Al
                     : (wave == 2) ? Bh : Bl;
  const bool isB = wave >= 2;
  const int lrow = lane >> 2;
  const int lchunk = (lane & 3) ^ (lrow & 3);

  f32x4 acc[4][4];
#pragma unroll
  for (int mi = 0; mi < 4; ++mi)
#pragma unroll
    for (int ni = 0; ni < 4; ++ni) acc[mi][ni] = (f32x4)0.0f;

  for (int k0 = 0; k0 < H_; k0 += 32) {
    __syncthreads();
#pragma unroll
    for (int c16 = 0; c16 < 8; ++c16) {
      const int r = c16 * 16 + lrow;
      const int grow = isB ? min(n0 + r, V_ - 1) : (m0 + r);
      const unsigned short* src = gp + (size_t)grow * H_ + k0 + lchunk * 8;
      __builtin_amdgcn_global_load_lds(
          (const __attribute__((address_space(1))) void*)src,
          (__attribute__((address_space(3))) void*)(lp + c16 * 512), 16, 0, 0);
    }
    __syncthreads();

    bf16x8 ah[4], al[4], bh[4], bl[4];
#pragma unroll
    for (int i = 0; i < 4; ++i) {
      ah[i] = *(const bf16x8*)&Ah[(wm * 64 + i * 16 + lr) * 32 + cxr];
      al[i] = *(const bf16x8*)&Al[(wm * 64 + i * 16 + lr) * 32 + cxr];
      bh[i] = *(const bf16x8*)&Bh[(wn * 64 + i * 16 + lr) * 32 + cxr];
      bl[i] = *(const bf16x8*)&Bl[(wn * 64 + i * 16 + lr) * 32 + cxr];
    }
#pragma unroll
    for (int mi = 0; mi < 4; ++mi)
#pragma unroll
      for (int ni = 0; ni < 4; ++ni) {
        acc[mi][ni] = __builtin_amdgcn_mfma_f32_16x16x32_bf16(
            ah[mi], bh[ni], acc[mi][ni], 0, 0, 0);
        acc[mi][ni] = __builtin_amdgcn_mfma_f32_16x16x32_bf16(
            ah[mi], bl[ni], acc[mi][ni], 0, 0, 0);
        acc[mi][ni] = __builtin_amdgcn_mfma_f32_16x16x32_bf16(
            al[mi], bh[ni], acc[mi][ni], 0, 0, 0);
      }
  }

  // C-write (logits + bias)
#pragma unroll
  for (int ni = 0; ni < 4; ++ni) {
    const int v = n0 + wn * 64 + ni * 16 + lr;
    if (v >= V_) continue;
    const float bias = b_fc[v];
#pragma unroll
    for (int mi = 0; mi < 4; ++mi) {
      const int mrow = m0 + wm * 64 + mi * 16 + lg * 4;
#pragma unroll
      for (int r = 0; r < 4; ++r)
        out[(size_t)(mrow + r) * V_ + v] = acc[mi][ni][r] + bias;
    }
  }

  // fused softmax partials over this block's 128 rows (one batch slice)
  float pm[4], psum[4];
#pragma unroll
  for (int ni = 0; ni < 4; ++ni) {
    const int v = n0 + wn * 64 + ni * 16 + lr;
    float m = -3.4e38f, s = 0.f;
    if (v < V_) {
      const float bias = b_fc[v];
#pragma unroll
      for (int mi = 0; mi < 4; ++mi)
#pragma unroll
        for (int r = 0; r < 4; ++r)
          m = fmaxf(m, acc[mi][ni][r] + bias);
#pragma unroll
      for (int mi = 0; mi < 4; ++mi)
#pragma unroll
        for (int r = 0; r < 4; ++r)
          s += __expf(acc[mi][ni][r] + bias - m);
    }
    // merge across the 4 row-groups (lane>>4): xor 16, 32
#pragma unroll
    for (int d = 16; d <= 32; d <<= 1) {
      const float om = __shfl_xor(m, d);
      const float os = __shfl_xor(s, d);
      const float nm = fmaxf(m, om);
      s = s * __expf(m - nm) + os * __expf(om - nm);
      m = nm;
    }
    pm[ni] = m;
    psum[ni] = s;
  }
  __syncthreads();
  if (lg == 0) {
#pragma unroll
    for (int ni = 0; ni < 4; ++ni)
      sstat[wm][wn][ni][lr] = make_float2(pm[ni], psum[ni]);
  }
  __syncthreads();
  if (wm == 0 && lg == 0) {
#pragma unroll
    for (int ni = 0; ni < 4; ++ni) {
      const int v = n0 + wn * 64 + ni * 16 + lr;
      if (v < V_) {
        const float2 s0 = sstat[0][wn][ni][lr];
        const float2 s1 = sstat[1][wn][ni][lr];
        const float nm = fmaxf(s0.x, s1.x);
        const float ss =
            s0.y * __expf(s0.x - nm) + s1.y * __expf(s1.x - nm);
        pstats[(size_t)blockIdx.x * V_ + v] = make_float2(nm, ss);
      }
    }
  }
}

// ---------------------------------------------------------------------------
// K4a (merge): stats[b,v] = merge of 4 m-block partials (10 MB read,
// replaces the 327 MB column-strided logits re-read).
// ---------------------------------------------------------------------------
__global__ __launch_bounds__(256) void k4_merge(const float2* __restrict__ pstats,
                                                float* __restrict__ stats) {
  const int gg = blockIdx.x * 256 + threadIdx.x;  // b*V + v, exact grid
  const int b = gg / V_;
  const int v = gg - b * V_;
  float m = -3.4e38f, s = 0.f;
#pragma unroll
  for (int i = 0; i < 4; ++i) {
    const float2 p = pstats[(size_t)(4 * b + i) * V_ + v];
    const float nm = fmaxf(m, p.x);
    s = s * __expf(m - nm) + p.y * __expf(p.x - nm);
    m = nm;
  }
  stats[2 * gg] = m;
  stats[2 * gg + 1] = 1.f / s;
}

// ---------------------------------------------------------------------------
// K4b: normalize, float4, no int-div: grid (ceil(V/1024), BS).
// ---------------------------------------------------------------------------
__global__ __launch_bounds__(256) void k4_norm(float* __restrict__ logits,
                                               const float* __restrict__ stats) {
  const int bs = blockIdx.y;
  const int b = bs >> 9;
  const int v0 = blockIdx.x * 1024 + threadIdx.x * 4;
  if (v0 >= V_) return;
  float* p = logits + (size_t)bs * V_ + v0;
  const float4 l = *(const float4*)p;
  const float4 s01 = *(const float4*)&stats[2 * (b * V_ + v0)];
  const float4 s23 = *(const float4*)&stats[2 * (b * V_ + v0) + 4];
  float4 o;
  o.x = __expf(l.x - s01.x) * s01.y;
  o.y = __expf(l.y - s01.z) * s01.w;
  o.z = __expf(l.z - s23.x) * s23.y;
  o.w = __expf(l.w - s23.z) * s23.w;
  *(float4*)p = o;
}

extern "C" void kernel_launch(void* const* d_in, const int* in_sizes, int n_in,
                              void* d_out, int out_size, void* d_ws,
                              size_t ws_size, hipStream_t stream) {
  const float* x    = (const float*)d_in[0];
  const float* W_ih = (const float*)d_in[1];
  const float* W_hh = (const float*)d_in[2];
  const float* b_ih = (const float*)d_in[3];
  const float* b_hh = (const float*)d_in[4];
  const float* W_fc = (const float*)d_in[5];
  const float* b_fc = (const float*)d_in[6];
  float* out = (float*)d_out;

  // ws layout (floats): xw | hs | stats | wfc_hi | wfc_lo | pstats
  //   part (256 KB, scan-only) ALIASES wfc_hi (k2 done before k5_wfc)
  //   hs_hi/hs_lo (bf16) ALIAS xw (dead after k2)
  float* ws = (float*)d_ws;
  float* xw    = ws;
  float* hs    = xw + (size_t)BS_ * H_;
  float* stats = hs + (size_t)BS_ * H_;
  unsigned short* wfc_hi = (unsigned short*)(stats + (size_t)2 * B_ * V_);
  unsigned short* wfc_lo = wfc_hi + (size_t)V_ * H_;
  float2* pstats = (float2*)(wfc_lo + (size_t)V_ * H_);  // 64*V float2
  u64* part = (u64*)wfc_hi;
  unsigned short* hs_hi = (unsigned short*)xw;
  unsigned short* hs_lo = hs_hi + (size_t)BS_ * H_;

  k0_init<<<PART_WORDS / 256, 256, 0, stream>>>(part);
  k1_xw<<<dim3(BS_ / 16, H_ / 16), 256, 0, stream>>>(x, W_ih, b_ih, b_hh, xw);
  k2_scan<<<NBLK, 512, 0, stream>>>(xw, W_hh, hs, part);
  k5_split<<<((V_ * H_ / 4) + 255) / 256, 256, 0, stream>>>(W_fc, wfc_hi,
                                                            wfc_lo, V_ * H_ / 4);
  k5_split<<<((BS_ * H_ / 4) + 255) / 256, 256, 0, stream>>>(
      hs, hs_hi, hs_lo, BS_ * H_ / 4);
  k3_logits<<<dim3(BS_ / 128, (V_ + 127) / 128), 256, 0, stream>>>(
      hs_hi, hs_lo, wfc_hi, wfc_lo, b_fc, out, pstats);
  k4_merge<<<(B_ * V_) / 256, 256, 0, stream>>>(pstats, stats);
  k4_norm<<<dim3((V_ + 1023) / 1024, BS_), 256, 0, stream>>>(out, stats);
}